// Round 7
// baseline (155.122 us; speedup 1.0000x reference)
//
#include <hip/hip_runtime.h>

#define NN 768
#define IN_F 68
#define KNN 8
#define EO 32
#define FEAT 264
#define HALF_FEAT 132
#define EMB 32
#define NPAIR 294528   // 768*767/2

typedef __attribute__((ext_vector_type(8))) short bf16x8;
typedef __attribute__((ext_vector_type(4))) float f32x4;

// pack hi16(x1):hi16(x0) into one dword — bf16 truncation of two floats, 1 v_perm
static __device__ __forceinline__ int pack_chop2(float x0, float x1) {
  return __builtin_amdgcn_perm(__float_as_uint(x1), __float_as_uint(x0), 0x07060302);
}
static __device__ __forceinline__ float chop(float x) {
  return __uint_as_float(__float_as_uint(x) & 0xffff0000u);
}

// Session ledger (MI355X sync costs, measured r1-r6):
//   grid barrier (any impl): 230-400us @1538 blocks  -> never use
//   cross-XCD i64 atomics:   ~60us per ~600K RMWs    -> never bulk-use
//   kernel boundary:         ~10-20us                -> cheapest sync
//   widening A to 2 waves:   -3us only               -> kernels are latency-floor bound
// This round: remove one boundary by folding D (u/v/c0) into E per-block
// (block-local recompute, zero cross-block communication).

// ---------------- Kernel A: top-8 neighbors + EdgeConv1 (2 waves) ----------
__global__ void __launch_bounds__(128) topk_ec1_kernel(
    const float* __restrict__ feat0, const float* __restrict__ feat1,
    const float* __restrict__ w1, const float* __restrict__ b1,
    const float* __restrict__ w2, const float* __restrict__ b2,
    int* __restrict__ idx_out, float* __restrict__ e1out)
{
  const int i = blockIdx.x, g = blockIdx.y;
  const float* __restrict__ feat = g ? feat1 : feat0;
  const int tid = threadIdx.x;
  const int lane = tid & 63, wv = tid >> 6;

  __shared__ unsigned long long keys[128*8];
  __shared__ int nbr[8];
  __shared__ float gl[KNN*IN_F];
  __shared__ float hsh[EO];
  __shared__ float part1[2][EO];
  __shared__ float part2[4][EO];

  const float4 ci = *(const float4*)(feat + i*IN_F);

  float4 cand[6];
#pragma unroll
  for (int t = 0; t < 6; t++)
    cand[t] = *(const float4*)(feat + (tid + 128*t)*IN_F);

  float bd[8]; int bidx[8];
#pragma unroll
  for (int k = 0; k < 8; k++) { bd[k] = 1e30f; bidx[k] = 0; }
#pragma unroll
  for (int t = 0; t < 6; t++) {
    const int j = tid + 128*t;
    float d = fabsf(ci.x - cand[t].x);   // same sequential add order as ref sum(-1)
    d += fabsf(ci.y - cand[t].y);
    d += fabsf(ci.z - cand[t].z);
    d += fabsf(ci.w - cand[t].w);
    if (d < bd[7]) {
#pragma unroll
      for (int k = 7; k >= 1; k--) {
        if (d < bd[k-1])    { bd[k] = bd[k-1]; bidx[k] = bidx[k-1]; }
        else if (d < bd[k]) { bd[k] = d;       bidx[k] = j; }
      }
      if (d < bd[0]) { bd[0] = d; bidx[0] = j; }
    }
  }
#pragma unroll
  for (int k = 0; k < 8; k++)
    keys[tid*8+k] = ((unsigned long long)__float_as_uint(bd[k]) << 32) | (unsigned)bidx[k];
  __syncthreads();

  // wave 0 merges 128 sorted lists: each lane tracks 2 list heads.
  if (wv == 0) {
    int posA = 0, posB = 0;
#pragma unroll
    for (int r = 0; r < 8; r++) {
      unsigned long long ha = keys[lane*8 + posA];
      unsigned long long hb = keys[(lane+64)*8 + posB];
      unsigned long long mn = ha < hb ? ha : hb;
#pragma unroll
      for (int s = 32; s >= 1; s >>= 1) {
        unsigned long long o = __shfl_xor(mn, s, 64);
        mn = (o < mn) ? o : mn;
      }
      if (ha == mn) posA++;
      else if (hb == mn) posB++;
      if (lane == 0) {
        int nb = (int)(mn & 0xffffffffull);
        nbr[r] = nb;
        idx_out[(g*NN+i)*8 + r] = nb;
      }
    }
  }
  __syncthreads();

  for (int z = tid; z < KNN*17; z += 128) {
    int k = z / 17, q = z - k*17;
    *(float4*)&gl[k*IN_F + q*4] = *(const float4*)(feat + nbr[k]*IN_F + q*4);
  }
  __syncthreads();

  // layer1: wave wv owns k-chains {4wv..4wv+3}; half-wave hf owns c-chunk.
  const int e = lane & 31, hf = lane >> 5;
  float ak[4];
#pragma unroll
  for (int k = 0; k < 4; k++) ak[k] = 0.f;
  const int cbeg = hf*34;
  const int kbase = wv*4;
  for (int c = cbeg; c < cbeg+34; c++) {
#pragma unroll
    for (int k = 0; k < 4; k++)
      ak[k] += gl[(kbase+k)*IN_F+c] * w1[(c*8+kbase+k)*EO + e];
  }
  float acc = (ak[0]+ak[1])+(ak[2]+ak[3]);
  acc += __shfl_xor(acc, 32, 64);
  if (hf == 0) part1[wv][e] = acc;
  __syncthreads();
  if (tid < 32) {
    float h = part1[0][tid] + part1[1][tid] + b1[tid];
    hsh[tid] = fmaxf(h, 0.01f*h);
  }
  __syncthreads();

  // layer2: quarter qq owns m-range [8qq, 8qq+8).
  const int qq = tid >> 5, ee = tid & 31;
  {
    float o0=0.f, o1=0.f, o2=0.f, o3=0.f;
    const int mbeg = qq*8;
#pragma unroll
    for (int m = mbeg; m < mbeg+8; m += 4) {
      o0 += hsh[m+0] * w2[(m+0)*EO + ee];
      o1 += hsh[m+1] * w2[(m+1)*EO + ee];
      o2 += hsh[m+2] * w2[(m+2)*EO + ee];
      o3 += hsh[m+3] * w2[(m+3)*EO + ee];
    }
    part2[qq][ee] = ((o0+o1)+(o2+o3));
  }
  __syncthreads();
  if (tid < 32) {
    float o = b2[tid] + ((part2[0][tid]+part2[1][tid])+(part2[2][tid]+part2[3][tid]));
    o = fmaxf(o, 0.01f*o);
    e1out[(g*NN+i)*EO + tid] = o;
  }
}

// ---------------- Kernel B: EdgeConv2 ----------------
__global__ void __launch_bounds__(64) ec2_kernel(
    const int* __restrict__ idx, const float* __restrict__ e1,
    const float* __restrict__ w1, const float* __restrict__ b1,
    const float* __restrict__ w2, const float* __restrict__ b2,
    float* __restrict__ e2out)
{
  const int i = blockIdx.x, g = blockIdx.y;
  const int lane = threadIdx.x;
  __shared__ float gl[KNN*EO];
  __shared__ float hsh[EO];
  {
    const int k = lane >> 3, q = lane & 7;
    const int nb = idx[(g*NN+i)*8 + k];
    *(float4*)&gl[k*EO + q*4] = *(const float4*)(e1 + (g*NN+nb)*EO + q*4);
  }
  __syncthreads();
  const int e = lane & 31, hf = lane >> 5;
  float ak[8];
#pragma unroll
  for (int k = 0; k < 8; k++) ak[k] = 0.f;
  const int cbeg = hf*16;
  for (int c = cbeg; c < cbeg+16; c++) {
#pragma unroll
    for (int k = 0; k < 8; k++)
      ak[k] += gl[k*EO+c] * w1[(c*8+k)*EO + e];
  }
  float acc = ((ak[0]+ak[1])+(ak[2]+ak[3])) + ((ak[4]+ak[5])+(ak[6]+ak[7]));
  acc += __shfl_xor(acc, 32, 64);
  if (hf == 0) {
    float h = acc + b1[e];
    hsh[e] = fmaxf(h, 0.01f*h);
  }
  __syncthreads();
  if (lane < 32) {
    float o0=0.f, o1=0.f, o2=0.f, o3=0.f;
#pragma unroll
    for (int m = 0; m < 32; m += 4) {
      o0 += hsh[m+0] * w2[(m+0)*EO + lane];
      o1 += hsh[m+1] * w2[(m+1)*EO + lane];
      o2 += hsh[m+2] * w2[(m+2)*EO + lane];
      o3 += hsh[m+3] * w2[(m+3)*EO + lane];
    }
    float o = b2[lane] + ((o0+o1)+(o2+o3));
    o = fmaxf(o, 0.01f*o);
    e2out[(g*NN+i)*EO + lane] = o;
  }
}

// ---------------- Kernel C: BN stats (weighted node sums, shfl reduce) ----------------
__global__ void __launch_bounds__(256) stats_kernel(
    const float* __restrict__ feat0, const float* __restrict__ feat1,
    const float* __restrict__ e1, const float* __restrict__ e2,
    const float* __restrict__ bn_g,
    float* __restrict__ mu_out, float* __restrict__ sg_out)
{
  const int c = blockIdx.x;   // 0..131
  const int tid = threadIdx.x;
  double s1=0, s2=0, q1=0, q2=0;
  for (int t = tid; t < 2*NN; t += 256) {
    int g = t >= NN;
    int i = t - g*NN;
    float val;
    if (c < IN_F)      val = (g ? feat1 : feat0)[i*IN_F + c];
    else if (c < 100)  val = e1[(g*NN+i)*EO + (c-IN_F)];
    else               val = e2[(g*NN+i)*EO + (c-100)];
    double dv = val;
    double wf = (double)(NN-1-i), wsnd = (double)i;
    s1 += wf*dv;  s2 += wsnd*dv;
    double dq = dv*dv;
    q1 += wf*dq;  q2 += wsnd*dq;
  }
#pragma unroll
  for (int off = 32; off >= 1; off >>= 1) {
    s1 += __shfl_xor(s1, off, 64);
    s2 += __shfl_xor(s2, off, 64);
    q1 += __shfl_xor(q1, off, 64);
    q2 += __shfl_xor(q2, off, 64);
  }
  __shared__ double red[4][4];
  const int w = tid >> 6;
  if ((tid & 63) == 0) { red[w][0]=s1; red[w][1]=s2; red[w][2]=q1; red[w][3]=q2; }
  __syncthreads();
  if (tid == 0) {
    double t0 = red[0][0]+red[1][0]+red[2][0]+red[3][0];
    double t1 = red[0][1]+red[1][1]+red[2][1]+red[3][1];
    double t2 = red[0][2]+red[1][2]+red[2][2]+red[3][2];
    double t3 = red[0][3]+red[1][3]+red[2][3]+red[3][3];
    const double M2 = 2.0 * (double)NPAIR;
    double mu1 = t0/M2, mu2 = t1/M2;
    double v1 = t2/M2 - mu1*mu1;
    double v2 = t3/M2 - mu2*mu2;
    mu_out[c]           = (float)mu1;
    mu_out[HALF_FEAT+c] = (float)mu2;
    sg_out[c]           = (float)((double)bn_g[c] / sqrt(v1 + 1e-5));
    sg_out[HALF_FEAT+c] = (float)((double)bn_g[HALF_FEAT+c] / sqrt(v2 + 1e-5));
  }
}

// ---------------- Kernel E': fused u/v/c0 + pair MLP (split-bf16 MFMA) ----
// Former kernel D is folded in: each block recomputes u for its 16 a-rows
// and v for its 16 b-rows from feat/e1/e2 and sg (block-local, zero
// cross-block traffic), plus c0 (264x32 MAC spread over 256 threads).
// Saves one kernel boundary (~15-20us, session ledger).
__global__ void __launch_bounds__(256) pair_kernel(
    const float* __restrict__ feat0, const float* __restrict__ feat1,
    const float* __restrict__ e1, const float* __restrict__ e2,
    const float* __restrict__ sg, const float* __restrict__ mu,
    const float* __restrict__ bn_b,
    const float* __restrict__ lin1_w, const float* __restrict__ lin1_b,
    const float* __restrict__ lin2_w, const float* __restrict__ lin2_b,
    const float* __restrict__ lin3_w, const float* __restrict__ lin3_b,
    float2* __restrict__ out)
{
  const int g = blockIdx.y;
  const float* __restrict__ feat = g ? feat1 : feat0;
  int rem = blockIdx.x;        // 0..1175 triangular tile id
  int a = 0;
  while (rem >= 48 - a) { rem -= 48 - a; a++; }
  const int b = a + rem;

  // xab: x*sg staged for both tiles (phase 0/1), then ALIASED as the 4
  // per-wave wbuf scratch areas in phase 2 (needs 2304 floats <= 4352).
  __shared__ float xab[2][16][136];
  __shared__ float su[16*36], sv[16*36];
  __shared__ float c0p[8][EMB];
  __shared__ float c0s[EMB];

  const int tid = threadIdx.x;

  // ---- phase 0: gather x*sg for a-tile and b-tile nodes ----
  {
    const int r = tid >> 4, q = tid & 15;
    const int ia = a*16 + r, ib = b*16 + r;
    for (int c = q; c < HALF_FEAT; c += 16) {
      float va, vb;
      if (c < IN_F)      { va = feat[ia*IN_F + c];            vb = feat[ib*IN_F + c]; }
      else if (c < 100)  { va = e1[(g*NN+ia)*EO + (c-IN_F)];  vb = e1[(g*NN+ib)*EO + (c-IN_F)]; }
      else               { va = e2[(g*NN+ia)*EO + (c-100)];   vb = e2[(g*NN+ib)*EO + (c-100)]; }
      xab[0][r][c] = va * sg[c];
      xab[1][r][c] = vb * sg[HALF_FEAT + c];
    }
  }
  // c0 partials: group grp handles 33 channels (8*33 = 264)
  {
    const int e = tid & 31, grp = tid >> 5;
    float p0=0.f, p1=0.f, p2=0.f;
    const int cb = grp*33;
    for (int c = cb; c < cb+33; c += 3) {
      p0 += (bn_b[c+0] - mu[c+0]*sg[c+0]) * lin1_w[(c+0)*EMB + e];
      p1 += (bn_b[c+1] - mu[c+1]*sg[c+1]) * lin1_w[(c+1)*EMB + e];
      p2 += (bn_b[c+2] - mu[c+2]*sg[c+2]) * lin1_w[(c+2)*EMB + e];
    }
    c0p[grp][e] = (p0+p1)+p2;
  }
  __syncthreads();

  // ---- phase 1: u (su) and v (sv) tiles; same chain order as old kernel D
  {
    const int e = tid & 31, rr = tid >> 5;   // rr 0..7; rows rr and rr+8
    float u0a=0.f,u0b=0.f,u0c=0.f,u0d=0.f, u1a=0.f,u1b=0.f,u1c=0.f,u1d=0.f;
    float v0a=0.f,v0b=0.f,v0c=0.f,v0d=0.f, v1a=0.f,v1b=0.f,v1c=0.f,v1d=0.f;
    for (int c = 0; c < HALF_FEAT; c += 4) {
      const float w0 = lin1_w[(c+0)*EMB + e];
      const float w1_ = lin1_w[(c+1)*EMB + e];
      const float w2_ = lin1_w[(c+2)*EMB + e];
      const float w3_ = lin1_w[(c+3)*EMB + e];
      const float z0 = lin1_w[(HALF_FEAT+c+0)*EMB + e];
      const float z1 = lin1_w[(HALF_FEAT+c+1)*EMB + e];
      const float z2 = lin1_w[(HALF_FEAT+c+2)*EMB + e];
      const float z3 = lin1_w[(HALF_FEAT+c+3)*EMB + e];
      const float4 xa0 = *(const float4*)&xab[0][rr][c];
      const float4 xa1 = *(const float4*)&xab[0][rr+8][c];
      const float4 xb0 = *(const float4*)&xab[1][rr][c];
      const float4 xb1 = *(const float4*)&xab[1][rr+8][c];
      u0a += xa0.x*w0; u0b += xa0.y*w1_; u0c += xa0.z*w2_; u0d += xa0.w*w3_;
      u1a += xa1.x*w0; u1b += xa1.y*w1_; u1c += xa1.z*w2_; u1d += xa1.w*w3_;
      v0a += xb0.x*z0; v0b += xb0.y*z1;  v0c += xb0.z*z2;  v0d += xb0.w*z3;
      v1a += xb1.x*z0; v1b += xb1.y*z1;  v1c += xb1.z*z2;  v1d += xb1.w*z3;
    }
    su[rr*36 + e]     = (u0a+u0b)+(u0c+u0d);
    su[(rr+8)*36 + e] = (u1a+u1b)+(u1c+u1d);
    sv[rr*36 + e]     = (v0a+v0b)+(v0c+v0d);
    sv[(rr+8)*36 + e] = (v1a+v1b)+(v1c+v1d);
  }
  if (tid < EMB) {
    float s = 0.f;
#pragma unroll
    for (int gq = 0; gq < 8; gq++) s += c0p[gq][tid];
    c0s[tid] = lin1_b[tid] + s;
  }
  __syncthreads();   // su/sv/c0s ready; xab reads done -> safe to alias wbuf

  // ---- phase 2: pair MLP via split-bf16 MFMA (identical to prior kernel E)
  const int lane = tid & 63, w = tid >> 6;
  const int q = lane & 15, kg = lane >> 4;   // q: m/n index, kg: k-group

  union { int i[4]; bf16x8 v; } whi0, wlo0, whi1, wlo1;
#pragma unroll
  for (int d = 0; d < 4; d++) {
    float w0a = lin2_w[(kg*8+2*d)*32 + q];
    float w0b = lin2_w[(kg*8+2*d+1)*32 + q];
    float w1a = lin2_w[(kg*8+2*d)*32 + 16 + q];
    float w1b = lin2_w[(kg*8+2*d+1)*32 + 16 + q];
    whi0.i[d] = pack_chop2(w0a, w0b);
    wlo0.i[d] = pack_chop2(w0a - chop(w0a), w0b - chop(w0b));
    whi1.i[d] = pack_chop2(w1a, w1b);
    wlo1.i[d] = pack_chop2(w1a - chop(w1a), w1b - chop(w1b));
  }
  float svc[8];
#pragma unroll
  for (int jj = 0; jj < 8; jj++)
    svc[jj] = sv[q*36 + kg*8 + jj] + c0s[kg*8+jj];
  float2 w3v[8]; float b2v[8];
#pragma unroll
  for (int jj = 0; jj < 8; jj++) {
    w3v[jj] = ((const float2*)lin3_w)[kg*8+jj];
    b2v[jj] = lin2_b[kg*8+jj];
  }
  const float b30 = lin3_b[0], b31 = lin3_b[1];

  float* wb = ((float*)xab) + w*576;   // alias: per-wave scratch in xab
#pragma unroll
  for (int t = 0; t < 4; t++) {
    const int ty = w*4 + t;
    const float4 sa = *(const float4*)&su[ty*36 + kg*8];
    const float4 sb = *(const float4*)&su[ty*36 + kg*8 + 4];
    float se[8] = {sa.x, sa.y, sa.z, sa.w, sb.x, sb.y, sb.z, sb.w};
    union { int i[4]; bf16x8 v; } ahi, alo;
#pragma unroll
    for (int d = 0; d < 4; d++) {
      float s0 = se[2*d]   + svc[2*d];
      float s1 = se[2*d+1] + svc[2*d+1];
      s0 = fmaxf(s0, 0.01f*s0);
      s1 = fmaxf(s1, 0.01f*s1);
      ahi.i[d] = pack_chop2(s0, s1);
      alo.i[d] = pack_chop2(s0 - chop(s0), s1 - chop(s1));
    }
    f32x4 acc0 = {0.f,0.f,0.f,0.f}, acc1 = {0.f,0.f,0.f,0.f};
    acc0 = __builtin_amdgcn_mfma_f32_16x16x32_bf16(ahi.v, whi0.v, acc0, 0,0,0);
    acc1 = __builtin_amdgcn_mfma_f32_16x16x32_bf16(ahi.v, whi1.v, acc1, 0,0,0);
    acc0 = __builtin_amdgcn_mfma_f32_16x16x32_bf16(ahi.v, wlo0.v, acc0, 0,0,0);
    acc1 = __builtin_amdgcn_mfma_f32_16x16x32_bf16(ahi.v, wlo1.v, acc1, 0,0,0);
    acc0 = __builtin_amdgcn_mfma_f32_16x16x32_bf16(alo.v, whi0.v, acc0, 0,0,0);
    acc1 = __builtin_amdgcn_mfma_f32_16x16x32_bf16(alo.v, whi1.v, acc1, 0,0,0);
#pragma unroll
    for (int r = 0; r < 4; r++) {
      wb[(kg*4+r)*36 + q]      = acc0[r];
      wb[(kg*4+r)*36 + 16 + q] = acc1[r];
    }
    float o0 = 0.f, o1 = 0.f;
#pragma unroll
    for (int jj = 0; jj < 8; jj++) {
      float h = wb[q*36 + kg*8 + jj] + b2v[jj];
      h = fmaxf(h, 0.01f*h);
      o0 += h * w3v[jj].x;
      o1 += h * w3v[jj].y;
    }
    o0 += __shfl_xor(o0, 16, 64); o0 += __shfl_xor(o0, 32, 64);
    o1 += __shfl_xor(o1, 16, 64); o1 += __shfl_xor(o1, 32, 64);
    const int i = a*16 + ty, j = b*16 + q;
    if (lane < 16 && j > i) {
      long p = (long)i*NN - (long)i*(i+1)/2 + (j - i - 1);
      out[(long)g*NPAIR + p] = make_float2(o0 + b30, o1 + b31);
    }
  }
}

extern "C" void kernel_launch(void* const* d_in, const int* in_sizes, int n_in,
                              void* d_out, int out_size, void* d_ws, size_t ws_size,
                              hipStream_t stream)
{
  const float* feat0  = (const float*)d_in[0];
  const float* feat1  = (const float*)d_in[1];
  const float* ec1_w1 = (const float*)d_in[2];
  const float* ec1_b1 = (const float*)d_in[3];
  const float* ec1_w2 = (const float*)d_in[4];
  const float* ec1_b2 = (const float*)d_in[5];
  const float* ec2_w1 = (const float*)d_in[6];
  const float* ec2_b1 = (const float*)d_in[7];
  const float* ec2_w2 = (const float*)d_in[8];
  const float* ec2_b2 = (const float*)d_in[9];
  const float* bn_g   = (const float*)d_in[10];
  const float* bn_b   = (const float*)d_in[11];
  const float* lin1_w = (const float*)d_in[12];
  const float* lin1_b = (const float*)d_in[13];
  const float* lin2_w = (const float*)d_in[14];
  const float* lin2_b = (const float*)d_in[15];
  const float* lin3_w = (const float*)d_in[16];
  const float* lin3_b = (const float*)d_in[17];

  char* ws = (char*)d_ws;
  int*   idx = (int*)  (ws + 0);
  float* e1  = (float*)(ws + 49152);
  float* e2  = (float*)(ws + 245760);
  float* mu  = (float*)(ws + 835584);
  float* sg  = (float*)(ws + 836640);

  topk_ec1_kernel<<<dim3(768,2), 128, 0, stream>>>(feat0, feat1, ec1_w1, ec1_b1,
                                                   ec1_w2, ec1_b2, idx, e1);
  ec2_kernel<<<dim3(768,2), 64, 0, stream>>>(idx, e1, ec2_w1, ec2_b1,
                                             ec2_w2, ec2_b2, e2);
  stats_kernel<<<dim3(132), 256, 0, stream>>>(feat0, feat1, e1, e2, bn_g, mu, sg);
  pair_kernel<<<dim3(1176,2), 256, 0, stream>>>(feat0, feat1, e1, e2, sg, mu, bn_b,
                                                lin1_w, lin1_b, lin2_w, lin2_b,
                                                lin3_w, lin3_b, (float2*)d_out);
}

// Round 8
// 130.653 us; speedup vs baseline: 1.1873x; 1.1873x over previous
//
#include <hip/hip_runtime.h>

#define NN 768
#define IN_F 68
#define KNN 8
#define EO 32
#define FEAT 264
#define HALF_FEAT 132
#define EMB 32
#define NPAIR 294528   // 768*767/2

typedef __attribute__((ext_vector_type(8))) short bf16x8;
typedef __attribute__((ext_vector_type(4))) float f32x4;

// pack hi16(x1):hi16(x0) into one dword — bf16 truncation of two floats, 1 v_perm
static __device__ __forceinline__ int pack_chop2(float x0, float x1) {
  return __builtin_amdgcn_perm(__float_as_uint(x1), __float_as_uint(x0), 0x07060302);
}
static __device__ __forceinline__ float chop(float x) {
  return __uint_as_float(__float_as_uint(x) & 0xffff0000u);
}

// Session ledger (MI355X, measured r1-r7):
//   grid barrier (any impl): 230-400us @1538 blocks -> never use
//   cross-XCD i64 atomics:   ~60us per ~600K RMWs   -> never bulk-use
//   kernel boundary:         ~5-15us                -> cheapest sync
//   D+E+1 boundary ~30us; A+B+C+3 boundaries ~104us (r6/r7 subtraction)
//   fusion-by-recompute with 49x redundancy (D into E): +20us -> reverted
// This round: coalesced float4 weight loads (4x fewer VMEM instrs) in the
// scalar MLP phases of A, B, D; per-thread owns a 4-wide e-column group.

// ---------------- Kernel A: top-8 neighbors + EdgeConv1 (2 waves) ----------
__global__ void __launch_bounds__(128) topk_ec1_kernel(
    const float* __restrict__ feat0, const float* __restrict__ feat1,
    const float* __restrict__ w1, const float* __restrict__ b1,
    const float* __restrict__ w2, const float* __restrict__ b2,
    int* __restrict__ idx_out, float* __restrict__ e1out)
{
  const int i = blockIdx.x, g = blockIdx.y;
  const float* __restrict__ feat = g ? feat1 : feat0;
  const int tid = threadIdx.x;
  const int lane = tid & 63, wv = tid >> 6;

  __shared__ unsigned long long keys[128*8];
  __shared__ int nbr[8];
  __shared__ float gl[KNN*IN_F];
  __shared__ float hsh[EO];
  __shared__ f32x4 part1[16][8];   // [sub][eg]
  __shared__ f32x4 part2[16][8];

  const float4 ci = *(const float4*)(feat + i*IN_F);

  float4 cand[6];
#pragma unroll
  for (int t = 0; t < 6; t++)
    cand[t] = *(const float4*)(feat + (tid + 128*t)*IN_F);

  float bd[8]; int bidx[8];
#pragma unroll
  for (int k = 0; k < 8; k++) { bd[k] = 1e30f; bidx[k] = 0; }
#pragma unroll
  for (int t = 0; t < 6; t++) {
    const int j = tid + 128*t;
    float d = fabsf(ci.x - cand[t].x);   // same sequential add order as ref sum(-1)
    d += fabsf(ci.y - cand[t].y);
    d += fabsf(ci.z - cand[t].z);
    d += fabsf(ci.w - cand[t].w);
    if (d < bd[7]) {
#pragma unroll
      for (int k = 7; k >= 1; k--) {
        if (d < bd[k-1])    { bd[k] = bd[k-1]; bidx[k] = bidx[k-1]; }
        else if (d < bd[k]) { bd[k] = d;       bidx[k] = j; }
      }
      if (d < bd[0]) { bd[0] = d; bidx[0] = j; }
    }
  }
#pragma unroll
  for (int k = 0; k < 8; k++)
    keys[tid*8+k] = ((unsigned long long)__float_as_uint(bd[k]) << 32) | (unsigned)bidx[k];
  __syncthreads();

  // wave 0 merges 128 sorted lists: each lane tracks 2 list heads.
  if (wv == 0) {
    int posA = 0, posB = 0;
#pragma unroll
    for (int r = 0; r < 8; r++) {
      unsigned long long ha = keys[lane*8 + posA];
      unsigned long long hb = keys[(lane+64)*8 + posB];
      unsigned long long mn = ha < hb ? ha : hb;
#pragma unroll
      for (int s = 32; s >= 1; s >>= 1) {
        unsigned long long o = __shfl_xor(mn, s, 64);
        mn = (o < mn) ? o : mn;
      }
      if (ha == mn) posA++;
      else if (hb == mn) posB++;
      if (lane == 0) {
        int nb = (int)(mn & 0xffffffffull);
        nbr[r] = nb;
        idx_out[(g*NN+i)*8 + r] = nb;
      }
    }
  }
  __syncthreads();

  for (int z = tid; z < KNN*17; z += 128) {
    int k = z / 17, q = z - k*17;
    *(float4*)&gl[k*IN_F + q*4] = *(const float4*)(feat + nbr[k]*IN_F + q*4);
  }
  __syncthreads();

  // ---- layer1, coalesced float4 weight loads ----
  // thread (sub = tid>>3 in 0..15, eg = tid&7) accumulates rows
  // r = sub + 16*t (t=0..33) of the 544-row (c*8+k) x 32 matrix for
  // e-columns [eg*4, eg*4+4). Per-wave w1 load = 8 rows x 32 floats dense.
  const int eg = tid & 7, sub = tid >> 3;
  {
    f32x4 a4 = {0.f,0.f,0.f,0.f};
    const float* wp = w1 + eg*4;
    for (int t = 0; t < 34; t++) {
      const int r = sub + 16*t;
      const int k = r & 7, c = r >> 3;
      const float s = gl[k*IN_F + c];
      a4 += s * *(const f32x4*)(wp + r*EO);
    }
    part1[sub][eg] = a4;
  }
  __syncthreads();
  if (tid < 32) {
    float h = b1[tid];
    const float* pp = (const float*)part1;   // [sub][eg][cm] = sub*32 + e
#pragma unroll
    for (int s = 0; s < 16; s++) h += pp[s*32 + tid];
    hsh[tid] = fmaxf(h, 0.01f*h);
  }
  __syncthreads();

  // ---- layer2 ----
  {
    const int m0 = sub*2;
    f32x4 a4 = hsh[m0]   * *(const f32x4*)(w2 + (m0+0)*EO + eg*4)
             + hsh[m0+1] * *(const f32x4*)(w2 + (m0+1)*EO + eg*4);
    part2[sub][eg] = a4;
  }
  __syncthreads();
  if (tid < 32) {
    float o = b2[tid];
    const float* pp = (const float*)part2;
#pragma unroll
    for (int s = 0; s < 16; s++) o += pp[s*32 + tid];
    o = fmaxf(o, 0.01f*o);
    e1out[(g*NN+i)*EO + tid] = o;
  }
}

// ---------------- Kernel B: EdgeConv2 (coalesced float4 weights) ----------
__global__ void __launch_bounds__(64) ec2_kernel(
    const int* __restrict__ idx, const float* __restrict__ e1,
    const float* __restrict__ w1, const float* __restrict__ b1,
    const float* __restrict__ w2, const float* __restrict__ b2,
    float* __restrict__ e2out)
{
  const int i = blockIdx.x, g = blockIdx.y;
  const int lane = threadIdx.x;
  __shared__ float gl[KNN*36];     // stride 36: kills 8-way bank conflict on
                                   // the k-strided read (36%32=4), keeps 16B align
  __shared__ float hsh[EO];
  __shared__ f32x4 partb[8][8];
  {
    const int k = lane >> 3, q = lane & 7;
    const int nb = idx[(g*NN+i)*8 + k];
    *(float4*)&gl[k*36 + q*4] = *(const float4*)(e1 + (g*NN+nb)*EO + q*4);
  }
  __syncthreads();
  const int eg = lane & 7, sub = lane >> 3;
  {
    f32x4 a4 = {0.f,0.f,0.f,0.f};
    const float* wp = w1 + eg*4;
    for (int t = 0; t < 32; t++) {
      const int r = sub + 8*t;           // k = sub, c = t
      const float s = gl[sub*36 + t];
      a4 += s * *(const f32x4*)(wp + r*EO);
    }
    partb[sub][eg] = a4;
  }
  __syncthreads();
  if (lane < 32) {
    float h = b1[lane];
    const float* pp = (const float*)partb;
#pragma unroll
    for (int s = 0; s < 8; s++) h += pp[s*32 + lane];
    hsh[lane] = fmaxf(h, 0.01f*h);
  }
  __syncthreads();
  {
    f32x4 a4 = {0.f,0.f,0.f,0.f};
#pragma unroll
    for (int j = 0; j < 4; j++) {
      const int m = sub*4 + j;
      a4 += hsh[m] * *(const f32x4*)(w2 + m*EO + eg*4);
    }
    partb[sub][eg] = a4;
  }
  __syncthreads();
  if (lane < 32) {
    float o = b2[lane];
    const float* pp = (const float*)partb;
#pragma unroll
    for (int s = 0; s < 8; s++) o += pp[s*32 + lane];
    o = fmaxf(o, 0.01f*o);
    e2out[(g*NN+i)*EO + lane] = o;
  }
}

// ---------------- Kernel C: BN stats (unchanged) ----------------
__global__ void __launch_bounds__(256) stats_kernel(
    const float* __restrict__ feat0, const float* __restrict__ feat1,
    const float* __restrict__ e1, const float* __restrict__ e2,
    const float* __restrict__ bn_g,
    float* __restrict__ mu_out, float* __restrict__ sg_out)
{
  const int c = blockIdx.x;   // 0..131
  const int tid = threadIdx.x;
  double s1=0, s2=0, q1=0, q2=0;
  for (int t = tid; t < 2*NN; t += 256) {
    int g = t >= NN;
    int i = t - g*NN;
    float val;
    if (c < IN_F)      val = (g ? feat1 : feat0)[i*IN_F + c];
    else if (c < 100)  val = e1[(g*NN+i)*EO + (c-IN_F)];
    else               val = e2[(g*NN+i)*EO + (c-100)];
    double dv = val;
    double wf = (double)(NN-1-i), wsnd = (double)i;
    s1 += wf*dv;  s2 += wsnd*dv;
    double dq = dv*dv;
    q1 += wf*dq;  q2 += wsnd*dq;
  }
#pragma unroll
  for (int off = 32; off >= 1; off >>= 1) {
    s1 += __shfl_xor(s1, off, 64);
    s2 += __shfl_xor(s2, off, 64);
    q1 += __shfl_xor(q1, off, 64);
    q2 += __shfl_xor(q2, off, 64);
  }
  __shared__ double red[4][4];
  const int w = tid >> 6;
  if ((tid & 63) == 0) { red[w][0]=s1; red[w][1]=s2; red[w][2]=q1; red[w][3]=q2; }
  __syncthreads();
  if (tid == 0) {
    double t0 = red[0][0]+red[1][0]+red[2][0]+red[3][0];
    double t1 = red[0][1]+red[1][1]+red[2][1]+red[3][1];
    double t2 = red[0][2]+red[1][2]+red[2][2]+red[3][2];
    double t3 = red[0][3]+red[1][3]+red[2][3]+red[3][3];
    const double M2 = 2.0 * (double)NPAIR;
    double mu1 = t0/M2, mu2 = t1/M2;
    double v1 = t2/M2 - mu1*mu1;
    double v2 = t3/M2 - mu2*mu2;
    mu_out[c]           = (float)mu1;
    mu_out[HALF_FEAT+c] = (float)mu2;
    sg_out[c]           = (float)((double)bn_g[c] / sqrt(v1 + 1e-5));
    sg_out[HALF_FEAT+c] = (float)((double)bn_g[HALF_FEAT+c] / sqrt(v2 + 1e-5));
  }
}

// ---------------- Kernel D: per-node u/v + c0 (coalesced float4 weights) --
__global__ void __launch_bounds__(64) uv_c0_kernel(
    const float* __restrict__ feat0, const float* __restrict__ feat1,
    const float* __restrict__ e1, const float* __restrict__ e2,
    const float* __restrict__ sg, const float* __restrict__ mu,
    const float* __restrict__ bn_b,
    const float* __restrict__ lin1_w, const float* __restrict__ lin1_b,
    float* __restrict__ u, float* __restrict__ v, float* __restrict__ c0g)
{
  const int i = blockIdx.x, g = blockIdx.y;
  const int t = threadIdx.x;
  if (i == NN) {
    if (g == 0 && t < EMB) {
      float a0=0.f, a1=0.f, a2=0.f, a3=0.f;
      for (int c = 0; c < FEAT; c += 4) {
        a0 += (bn_b[c+0] - mu[c+0]*sg[c+0]) * lin1_w[(c+0)*EMB + t];
        a1 += (bn_b[c+1] - mu[c+1]*sg[c+1]) * lin1_w[(c+1)*EMB + t];
        a2 += (bn_b[c+2] - mu[c+2]*sg[c+2]) * lin1_w[(c+2)*EMB + t];
        a3 += (bn_b[c+3] - mu[c+3]*sg[c+3]) * lin1_w[(c+3)*EMB + t];
      }
      c0g[t] = lin1_b[t] + ((a0+a1)+(a2+a3));
    }
    return;
  }
  __shared__ float x[HALF_FEAT];
  __shared__ f32x4 partd[8][8];
  for (int c = t; c < IN_F; c += 64) x[c] = (g ? feat1 : feat0)[i*IN_F + c];
  if (t < 32) x[IN_F + t]     = e1[(g*NN+i)*EO + t];
  else        x[100 + (t-32)] = e2[(g*NN+i)*EO + (t-32)];
  __syncthreads();
  // rows r = 0..263 of (sg .* lin1_w); subs 0..3 -> u rows, subs 4..7 -> v rows
  const int eg = t & 7, sub = t >> 3;
  {
    f32x4 a4 = {0.f,0.f,0.f,0.f};
    const int roff = (sub >= 4) ? HALF_FEAT : 0;
    const float* wp = lin1_w + eg*4;
    for (int tt = 0; tt < 33; tt++) {
      const int r = sub*33 + tt;
      const float xv = x[r - roff] * sg[r];
      a4 += xv * *(const f32x4*)(wp + r*EMB);
    }
    partd[sub][eg] = a4;
  }
  __syncthreads();
  const float* pp = (const float*)partd;   // [sub][eg][cm] = sub*32 + e
  if (t < 32) {
    float acc = (pp[0*32+t] + pp[1*32+t]) + (pp[2*32+t] + pp[3*32+t]);
    u[(g*NN+i)*EMB + t] = acc;
  } else {
    const int e = t - 32;
    float acc = (pp[4*32+e] + pp[5*32+e]) + (pp[6*32+e] + pp[7*32+e]);
    v[(g*NN+i)*EMB + e] = acc;
  }
}

// ---------------- Kernel E: pair MLP via split-bf16 MFMA (unchanged) ------
__global__ void __launch_bounds__(256) pair_kernel(
    const float* __restrict__ u, const float* __restrict__ v,
    const float* __restrict__ c0g,
    const float* __restrict__ lin2_w, const float* __restrict__ lin2_b,
    const float* __restrict__ lin3_w, const float* __restrict__ lin3_b,
    float2* __restrict__ out)
{
  const int g = blockIdx.y;
  int rem = blockIdx.x;        // 0..1175 triangular tile id
  int a = 0;
  while (rem >= 48 - a) { rem -= 48 - a; a++; }
  const int b = a + rem;

  __shared__ float su[16*36], sv[16*36];
  __shared__ float wbuf[4][16*36];
  const int tid = threadIdx.x;
  {
    int r = tid >> 5, c = tid & 31;
    su[r*36+c] = u[(g*NN + a*16 + r)*EMB + c];
    sv[r*36+c] = v[(g*NN + b*16 + r)*EMB + c];
    r += 8;
    su[r*36+c] = u[(g*NN + a*16 + r)*EMB + c];
    sv[r*36+c] = v[(g*NN + b*16 + r)*EMB + c];
  }
  __syncthreads();

  const int lane = tid & 63, w = tid >> 6;
  const int q = lane & 15, kg = lane >> 4;   // q: m/n index, kg: k-group

  union { int i[4]; bf16x8 v; } whi0, wlo0, whi1, wlo1;
#pragma unroll
  for (int d = 0; d < 4; d++) {
    float w0a = lin2_w[(kg*8+2*d)*32 + q];
    float w0b = lin2_w[(kg*8+2*d+1)*32 + q];
    float w1a = lin2_w[(kg*8+2*d)*32 + 16 + q];
    float w1b = lin2_w[(kg*8+2*d+1)*32 + 16 + q];
    whi0.i[d] = pack_chop2(w0a, w0b);
    wlo0.i[d] = pack_chop2(w0a - chop(w0a), w0b - chop(w0b));
    whi1.i[d] = pack_chop2(w1a, w1b);
    wlo1.i[d] = pack_chop2(w1a - chop(w1a), w1b - chop(w1b));
  }
  float svc[8];
#pragma unroll
  for (int jj = 0; jj < 8; jj++)
    svc[jj] = sv[q*36 + kg*8 + jj] + c0g[kg*8+jj];
  float2 w3v[8]; float b2v[8];
#pragma unroll
  for (int jj = 0; jj < 8; jj++) {
    w3v[jj] = ((const float2*)lin3_w)[kg*8+jj];
    b2v[jj] = lin2_b[kg*8+jj];
  }
  const float b30 = lin3_b[0], b31 = lin3_b[1];

  float* wb = wbuf[w];
#pragma unroll
  for (int t = 0; t < 4; t++) {
    const int ty = w*4 + t;
    const float4 sa = *(const float4*)&su[ty*36 + kg*8];
    const float4 sb = *(const float4*)&su[ty*36 + kg*8 + 4];
    float se[8] = {sa.x, sa.y, sa.z, sa.w, sb.x, sb.y, sb.z, sb.w};
    union { int i[4]; bf16x8 v; } ahi, alo;
#pragma unroll
    for (int d = 0; d < 4; d++) {
      float s0 = se[2*d]   + svc[2*d];
      float s1 = se[2*d+1] + svc[2*d+1];
      s0 = fmaxf(s0, 0.01f*s0);
      s1 = fmaxf(s1, 0.01f*s1);
      ahi.i[d] = pack_chop2(s0, s1);
      alo.i[d] = pack_chop2(s0 - chop(s0), s1 - chop(s1));
    }
    f32x4 acc0 = {0.f,0.f,0.f,0.f}, acc1 = {0.f,0.f,0.f,0.f};
    acc0 = __builtin_amdgcn_mfma_f32_16x16x32_bf16(ahi.v, whi0.v, acc0, 0,0,0);
    acc1 = __builtin_amdgcn_mfma_f32_16x16x32_bf16(ahi.v, whi1.v, acc1, 0,0,0);
    acc0 = __builtin_amdgcn_mfma_f32_16x16x32_bf16(ahi.v, wlo0.v, acc0, 0,0,0);
    acc1 = __builtin_amdgcn_mfma_f32_16x16x32_bf16(ahi.v, wlo1.v, acc1, 0,0,0);
    acc0 = __builtin_amdgcn_mfma_f32_16x16x32_bf16(alo.v, whi0.v, acc0, 0,0,0);
    acc1 = __builtin_amdgcn_mfma_f32_16x16x32_bf16(alo.v, whi1.v, acc1, 0,0,0);
#pragma unroll
    for (int r = 0; r < 4; r++) {
      wb[(kg*4+r)*36 + q]      = acc0[r];
      wb[(kg*4+r)*36 + 16 + q] = acc1[r];
    }
    float o0 = 0.f, o1 = 0.f;
#pragma unroll
    for (int jj = 0; jj < 8; jj++) {
      float h = wb[q*36 + kg*8 + jj] + b2v[jj];
      h = fmaxf(h, 0.01f*h);
      o0 += h * w3v[jj].x;
      o1 += h * w3v[jj].y;
    }
    o0 += __shfl_xor(o0, 16, 64); o0 += __shfl_xor(o0, 32, 64);
    o1 += __shfl_xor(o1, 16, 64); o1 += __shfl_xor(o1, 32, 64);
    const int i = a*16 + ty, j = b*16 + q;
    if (lane < 16 && j > i) {
      long p = (long)i*NN - (long)i*(i+1)/2 + (j - i - 1);
      out[(long)g*NPAIR + p] = make_float2(o0 + b30, o1 + b31);
    }
  }
}

extern "C" void kernel_launch(void* const* d_in, const int* in_sizes, int n_in,
                              void* d_out, int out_size, void* d_ws, size_t ws_size,
                              hipStream_t stream)
{
  const float* feat0  = (const float*)d_in[0];
  const float* feat1  = (const float*)d_in[1];
  const float* ec1_w1 = (const float*)d_in[2];
  const float* ec1_b1 = (const float*)d_in[3];
  const float* ec1_w2 = (const float*)d_in[4];
  const float* ec1_b2 = (const float*)d_in[5];
  const float* ec2_w1 = (const float*)d_in[6];
  const float* ec2_b1 = (const float*)d_in[7];
  const float* ec2_w2 = (const float*)d_in[8];
  const float* ec2_b2 = (const float*)d_in[9];
  const float* bn_g   = (const float*)d_in[10];
  const float* bn_b   = (const float*)d_in[11];
  const float* lin1_w = (const float*)d_in[12];
  const float* lin1_b = (const float*)d_in[13];
  const float* lin2_w = (const float*)d_in[14];
  const float* lin2_b = (const float*)d_in[15];
  const float* lin3_w = (const float*)d_in[16];
  const float* lin3_b = (const float*)d_in[17];

  char* ws = (char*)d_ws;
  int*   idx = (int*)  (ws + 0);
  float* e1  = (float*)(ws + 49152);
  float* e2  = (float*)(ws + 245760);
  float* u   = (float*)(ws + 442368);
  float* v   = (float*)(ws + 638976);
  float* mu  = (float*)(ws + 835584);
  float* sg  = (float*)(ws + 836640);
  float* c0g = (float*)(ws + 837696);

  topk_ec1_kernel<<<dim3(768,2), 128, 0, stream>>>(feat0, feat1, ec1_w1, ec1_b1,
                                                   ec1_w2, ec1_b2, idx, e1);
  ec2_kernel<<<dim3(768,2), 64, 0, stream>>>(idx, e1, ec2_w1, ec2_b1,
                                             ec2_w2, ec2_b2, e2);
  stats_kernel<<<dim3(132), 256, 0, stream>>>(feat0, feat1, e1, e2, bn_g, mu, sg);
  uv_c0_kernel<<<dim3(769,2), 64, 0, stream>>>(feat0, feat1, e1, e2, sg, mu, bn_b,
                                               lin1_w, lin1_b, u, v, c0g);
  pair_kernel<<<dim3(1176,2), 256, 0, stream>>>(u, v, c0g, lin2_w, lin2_b,
                                                lin3_w, lin3_b, (float2*)d_out);
}